// Round 11
// baseline (144.823 us; speedup 1.0000x reference)
//
#include <hip/hip_runtime.h>
#include <math.h>

#define NT 1024     // 16 waves, single block, single CU, 4 waves/SIMD (pinned)
#define EPT 4       // NT*EPT = 4096
#define NW (NT/64)  // 16 waves
#define NN 4096
#define MM 9
#define NIT 50

#define LAM  0.0625f            // 2^-4 (per-thread carry decay)
#define K1L  0.33203125f        // K1[3] = 85/256

// ---------- DPP cross-lane helpers (VALU pipe, no LDS) ----------
template<int CTRL, int RMASK>
__device__ __forceinline__ float dpp_add(float v) {
  int m = __builtin_amdgcn_update_dpp(0, __builtin_bit_cast(int, v), CTRL, RMASK, 0xf, false);
  return v + __builtin_bit_cast(float, m);
}
// full-wave sum; total lands in lane 63
__device__ __forceinline__ float wave_sum(float v) {
  v = dpp_add<0x111, 0xf>(v);   // row_shr:1
  v = dpp_add<0x112, 0xf>(v);   // row_shr:2
  v = dpp_add<0x114, 0xf>(v);   // row_shr:4
  v = dpp_add<0x118, 0xf>(v);   // row_shr:8
  v = dpp_add<0x142, 0xa>(v);   // row_bcast:15 -> rows 1,3
  v = dpp_add<0x143, 0xc>(v);   // row_bcast:31 -> rows 2,3
  return v;
}
// wave shift; invalid boundary lane receives `oldv`
template<int CTRL>
__device__ __forceinline__ float dpp_shift(float oldv, float v) {
  int m = __builtin_amdgcn_update_dpp(__builtin_bit_cast(int, oldv),
                                      __builtin_bit_cast(int, v), CTRL, 0xf, 0xf, false);
  return __builtin_bit_cast(float, m);
}
// broadcast lane l (uniform literal) -> SGPR
__device__ __forceinline__ float bcast_lane(float v, int l) {
  return __builtin_bit_cast(float, __builtin_amdgcn_readlane(__builtin_bit_cast(int, v), l));
}

// ---------- cyclic tridiagonal solve M p = r, EPT=4 ----------
// M = 25I - 10(P+P^T) = 5(2I-S+)(2I-S-). Carry decay/hop = 2^-4; 5-term
// truncation (2^-20). Coupling constant: K1L/(1-LAM^2) = (85/256)(256/255) = 1/3.
__device__ __forceinline__ void solveM_pre(const float r[EPT], float pl0[EPT],
                                           float2* __restrict__ s_sc, int t) {
  float yl[EPT];
  yl[3] = r[3] * 0.1f;
  yl[2] = fmaf(0.5f, yl[3], r[2] * 0.1f);
  yl[1] = fmaf(0.5f, yl[2], r[1] * 0.1f);
  yl[0] = fmaf(0.5f, yl[1], r[0] * 0.1f);
  pl0[0] = 0.5f * yl[0];
  pl0[1] = 0.5f * (yl[1] + pl0[0]);
  pl0[2] = 0.5f * (yl[2] + pl0[1]);
  pl0[3] = 0.5f * (yl[3] + pl0[2]);
  s_sc[t] = make_float2(yl[0], pl0[3]);
}

// window g[k] = s_sc[t-5+k], k=0..10
__device__ __forceinline__ void gather11(const float2* __restrict__ s_sc, int t, float2 g[11]) {
#pragma unroll
  for (int k = 0; k < 11; ++k) g[k] = s_sc[(t + k - 5) & (NT - 1)];
}

__device__ __forceinline__ void finish_own(const float2 g[11], const float pl0[EPT], float p[EPT]) {
  // backward carry (thread t+1 side), 5 terms
  float c = fmaf(LAM, fmaf(LAM, fmaf(LAM, fmaf(LAM, g[10].x, g[9].x), g[8].x), g[7].x), g[6].x);
  // forward carry: s1 over pl0last[t-1-k], s2 = sum lam^|m| yl0[t+m]
  float s1 = fmaf(LAM, fmaf(LAM, fmaf(LAM, fmaf(LAM, g[0].y, g[1].y), g[2].y), g[3].y), g[4].y);
  float s2 = fmaf(LAM, fmaf(LAM, fmaf(LAM, fmaf(LAM, g[1].x + g[9].x, g[2].x + g[8].x),
                                      g[3].x + g[7].x), g[4].x + g[6].x), g[5].x);
  float c2 = fmaf(1.0f / 3.0f, s2, s1);
  p[0] = fmaf(c2, 0.5f,    fmaf(c, 0.03125f,   pl0[0]));
  p[1] = fmaf(c2, 0.25f,   fmaf(c, 0.078125f,  pl0[1]));
  p[2] = fmaf(c2, 0.125f,  fmaf(c, 0.1640625f, pl0[2]));
  p[3] = fmaf(c2, 0.0625f, fmaf(c, K1L,        pl0[3]));
}

__global__ void __launch_bounds__(NT)
__attribute__((amdgpu_waves_per_eu(4, 4)))   // PIN 4 waves/SIMD: allocator gets (and must stay in) 128 VGPR
admm_kernel(const float* __restrict__ tg, const float* __restrict__ Ag,
            const float* __restrict__ x0, float* __restrict__ out) {
  __shared__ float2 s_sc[2][NT];                  // seeds (setup ping-pong; loop uses [0])
  __shared__ __align__(16) float s_wq[NW][12];    // per-wave 9-partials
  __shared__ float s_S[MM * MM];
  __shared__ float s_L[MM * MM];
  __shared__ float s_edge[NW][2];                 // [wave][0]=x[first], [1]=x[last]

  const int t = threadIdx.x;
  const int base = t * EPT;
  const int lane = t & 63, wave = t >> 6;

  // ---- load A slice (register-resident; all accesses compile-time-indexed) ----
  float A[MM][EPT];
#pragma unroll
  for (int m = 0; m < MM; ++m) {
    float4 a0 = *(const float4*)(Ag + m * NN + base);
    A[m][0] = a0.x; A[m][1] = a0.y; A[m][2] = a0.z; A[m][3] = a0.w;
  }

  // ---- load x0, target ----
  float x[EPT], tgt[EPT];
  {
    float4 v0 = *(const float4*)(x0 + base);
    x[0] = v0.x; x[1] = v0.y; x[2] = v0.z; x[3] = v0.w;
    float4 t0 = *(const float4*)(tg + base);
    tgt[0] = t0.x; tgt[1] = t0.y; tgt[2] = t0.z; tgt[3] = t0.w;
  }
  if (lane == 0)  s_edge[wave][0] = x[0];
  if (lane == 63) s_edge[wave][1] = x[3];

  // ---- b = A @ target: DPP reduce + lane-combine + readlane -> SGPRs ----
  float pq[MM];
#pragma unroll
  for (int m = 0; m < MM; ++m) {
    float s = 0.f;
#pragma unroll
    for (int j = 0; j < EPT; ++j) s = fmaf(A[m][j], tgt[j], s);
    pq[m] = wave_sum(s);
  }
  if (lane == 63) {
    *(float4*)&s_wq[wave][0] = make_float4(pq[0], pq[1], pq[2], pq[3]);
    *(float4*)&s_wq[wave][4] = make_float4(pq[4], pq[5], pq[6], pq[7]);
    s_wq[wave][8] = pq[8];
  }
  __syncthreads();
  float bb[MM];
  {
    float zv = 0.f;
    if (lane < MM) {
#pragma unroll
      for (int wv = 0; wv < NW; ++wv) zv += s_wq[wv][lane];
    }
#pragma unroll
    for (int m = 0; m < MM; ++m) bb[m] = bcast_lane(zv, m);
  }
  float bA[EPT];
#pragma unroll
  for (int j = 0; j < EPT; ++j) {
    float s = 0.f;
#pragma unroll
    for (int m = 0; m < MM; ++m) s = fmaf(bb[m], A[m][j], s);
    bA[j] = s;
  }

  // ---- S = I9 + A M^-1 A^T, keeping G columns for the GH fold ----
  float G[MM][EPT];
#pragma unroll
  for (int mc = 0; mc < MM; ++mc) {
    float rin[EPT];
#pragma unroll
    for (int j = 0; j < EPT; ++j) rin[j] = A[mc][j];
    float pl0[EPT];
    solveM_pre(rin, pl0, &s_sc[mc & 1][0], t);
    __syncthreads();
    float2 g[11];
    gather11(&s_sc[mc & 1][0], t, g);
    float gcol[EPT];
    finish_own(g, pl0, gcol);
#pragma unroll
    for (int j = 0; j < EPT; ++j) G[mc][j] = gcol[j];
#pragma unroll
    for (int k = 0; k < MM; ++k) {
      float s = 0.f;
#pragma unroll
      for (int j = 0; j < EPT; ++j) s = fmaf(A[k][j], gcol[j], s);
      pq[k] = wave_sum(s);
    }
    if (lane == 63) {
      *(float4*)&s_wq[wave][0] = make_float4(pq[0], pq[1], pq[2], pq[3]);
      *(float4*)&s_wq[wave][4] = make_float4(pq[4], pq[5], pq[6], pq[7]);
      s_wq[wave][8] = pq[8];
    }
    __syncthreads();
    if (wave == 0 && lane < MM) {
      float s = 0.f;
#pragma unroll
      for (int wv = 0; wv < NW; ++wv) s += s_wq[wv][lane];
      s_S[lane * MM + mc] = s + ((lane == mc) ? 1.f : 0.f);
    }
  }

  // ---- Sinv (Gauss-Jordan) + Cholesky Sinv = L L^T, fused on wave 0 ----
  if (t < 64) {
    float row[2 * MM];
#pragma unroll
    for (int j = 0; j < MM; ++j) row[j] = (t < MM) ? s_S[t * MM + j] : 0.f;
#pragma unroll
    for (int j = 0; j < MM; ++j) row[MM + j] = (j == t) ? 1.f : 0.f;
#pragma unroll
    for (int pp = 0; pp < MM; ++pp) {
      float pr[2 * MM];
#pragma unroll
      for (int j = 0; j < 2 * MM; ++j) pr[j] = __shfl(row[j], pp, 64);
      float rpiv = 1.f / pr[pp];
      float fct = row[pp] * rpiv;
#pragma unroll
      for (int j = 0; j < 2 * MM; ++j)
        row[j] = (t == pp) ? pr[j] * rpiv : fmaf(-fct, pr[j], row[j]);
    }
    float crow[MM];
#pragma unroll
    for (int j = 0; j < MM; ++j) crow[j] = row[MM + j];
#pragma unroll
    for (int k = 0; k < MM; ++k) {
      float dk = __shfl(crow[k], k, 64);
      float inv = 1.f / sqrtf(dk);
      crow[k] *= inv;
#pragma unroll
      for (int jj = k + 1; jj < MM; ++jj) {
        float ljk = __shfl(crow[k], jj, 64);   // L[jj][k]
        crow[jj] = fmaf(-crow[k], ljk, crow[jj]);
      }
    }
    if (t < MM) {
#pragma unroll
      for (int j = 0; j < MM; ++j) s_L[t * MM + j] = (t >= j) ? crow[j] : 0.f;
    }
  }
  __syncthreads();

  // ---- GH[m] = sum_{k>=m} G[k] * L[k][m] (fully unrolled, register-resident) ----
  float GH[MM][EPT];
#pragma unroll
  for (int m = 0; m < MM; ++m) {
    float lcol[MM];
#pragma unroll
    for (int k = 0; k < MM; ++k) lcol[k] = s_L[k * MM + m];
#pragma unroll
    for (int j = 0; j < EPT; ++j) {
      float s = 0.f;
#pragma unroll
      for (int k = 0; k < MM; ++k)
        if (k >= m) s = fmaf(G[k][j], lcol[k], s);
      GH[m][j] = s;
    }
  }

  // ---- ADMM iterations: 2 barriers each; scaled duals eta10=eta/10, tau5=tau/5;
  //      w eliminated via 5(w - tau5) = 5*max(x, -tau5), tau5' = x' - max(x, -tau5) ----
  float eta10[EPT], tau5[EPT];
#pragma unroll
  for (int j = 0; j < EPT; ++j) { eta10[j] = 0.f; tau5[j] = 0.f; }
  float u3prev = 0.f;

#pragma unroll 1
  for (int it = 0; it < NIT; ++it) {
    // --- neighbors via DPP wave-shift, edge lanes via LDS ---
    float oldm = 0.f, oldn = 0.f;
    if (lane == 0)  oldm = s_edge[(wave + NW - 1) & (NW - 1)][1];
    if (lane == 63) oldn = s_edge[(wave + 1) & (NW - 1)][0];
    float xm1 = dpp_shift<0x138>(oldm, x[3]);   // wave_shr1: lane i <- lane i-1
    if (it) {
      float xn4 = dpp_shift<0x130>(oldn, x[0]); // wave_shl1: lane i <- lane i+1
      eta10[3] += (xn4 - x[3]) - u3prev;        // deferred boundary dual
    }
    // --- u, m1, r ---
    float u[EPT], m1a[EPT], r[EPT];
#pragma unroll
    for (int j = 0; j < EPT; ++j) {
      float xprev = (j == 0) ? xm1 : x[j - 1];
      float v = xprev - x[j] + eta10[j];
      u[j] = copysignf(fmaxf(fabsf(v) - 1e-5f, 0.f), v);
      m1a[j] = fmaxf(x[j], -tau5[j]);
      r[j] = fmaf(10.f, u[j] - eta10[j], fmaf(5.f, m1a[j], bA[j]));
    }
    // --- zeta partials (from r directly) + DPP wave reduce ---
    float zp[MM];
#pragma unroll
    for (int m = 0; m < MM; ++m) {
      float s = 0.f;
#pragma unroll
      for (int j = 0; j < EPT; ++j) s = fmaf(GH[m][j], r[j], s);
      zp[m] = wave_sum(s);
    }
    if (lane == 63) {
      *(float4*)&s_wq[wave][0] = make_float4(zp[0], zp[1], zp[2], zp[3]);
      *(float4*)&s_wq[wave][4] = make_float4(zp[4], zp[5], zp[6], zp[7]);
      s_wq[wave][8] = zp[8];
    }
    // --- solveM local scans + seed publish ---
    float pl0[EPT];
    solveM_pre(r, pl0, &s_sc[0][0], t);
    __syncthreads();                            // BARRIER A
    // --- finish solve ---
    float2 g[11];
    gather11(&s_sc[0][0], t, g);
    float p[EPT];
    finish_own(g, pl0, p);
    // --- z: lanes 0..8 combine one component each, broadcast to SGPRs ---
    float zv = 0.f;
    if (lane < MM) {
#pragma unroll
      for (int wv = 0; wv < NW; ++wv) zv += s_wq[wv][lane];
    }
    float z[MM];
#pragma unroll
    for (int m = 0; m < MM; ++m) z[m] = bcast_lane(zv, m);
    // --- x = p - GH z (in place) ---
#pragma unroll
    for (int j = 0; j < EPT; ++j) {
      float s = p[j];
#pragma unroll
      for (int m = 0; m < MM; ++m) s = fmaf(-GH[m][j], z[m], s);
      x[j] = s;
    }
    if (lane == 0)  s_edge[wave][0] = x[0];
    if (lane == 63) s_edge[wave][1] = x[3];
    // --- duals: j=0..2 eta now, eta[3] deferred; tau all j now ---
#pragma unroll
    for (int j = 0; j < EPT - 1; ++j)
      eta10[j] += (x[j + 1] - x[j]) - u[j];
#pragma unroll
    for (int j = 0; j < EPT; ++j)
      tau5[j] = x[j] - m1a[j];
    u3prev = u[3];
    __syncthreads();                            // BARRIER B
  }

  // ---- output ----
  float4 o0;
  o0.x = x[0]; o0.y = x[1]; o0.z = x[2]; o0.w = x[3];
  *(float4*)(out + base) = o0;
}

extern "C" void kernel_launch(void* const* d_in, const int* in_sizes, int n_in,
                              void* d_out, int out_size, void* d_ws, size_t ws_size,
                              hipStream_t stream) {
  const float* target = (const float*)d_in[0];
  const float* A      = (const float*)d_in[1];
  const float* x0     = (const float*)d_in[2];
  admm_kernel<<<1, NT, 0, stream>>>(target, A, x0, (float*)d_out);
}

// Round 12
// 103.072 us; speedup vs baseline: 1.4051x; 1.4051x over previous
//
#include <hip/hip_runtime.h>
#include <math.h>

#define NT 512      // 8 waves, single block, single CU
#define EPT 8       // NT*EPT = 4096
#define NN 4096
#define MM 9
#define NIT 50

#define LAM  3.90625e-3f        // 2^-8 (per-thread carry decay)
#define LAM2 1.52587890625e-5f  // 2^-16
#define K1LAST 0.3333282470703125f

// ---------- DPP cross-lane helpers (VALU pipe, no LDS) ----------
template<int CTRL, int RMASK>
__device__ __forceinline__ float dpp_add(float v) {
  int m = __builtin_amdgcn_update_dpp(0, __builtin_bit_cast(int, v), CTRL, RMASK, 0xf, false);
  return v + __builtin_bit_cast(float, m);
}
// full-wave sum; total lands in lane 63
__device__ __forceinline__ float wave_sum(float v) {
  v = dpp_add<0x111, 0xf>(v);   // row_shr:1
  v = dpp_add<0x112, 0xf>(v);   // row_shr:2
  v = dpp_add<0x114, 0xf>(v);   // row_shr:4
  v = dpp_add<0x118, 0xf>(v);   // row_shr:8
  v = dpp_add<0x142, 0xa>(v);   // row_bcast:15 -> rows 1,3
  v = dpp_add<0x143, 0xc>(v);   // row_bcast:31 -> rows 2,3
  return v;
}
// wave shift; invalid boundary lane receives `oldv`
template<int CTRL>
__device__ __forceinline__ float dpp_shift(float oldv, float v) {
  int m = __builtin_amdgcn_update_dpp(__builtin_bit_cast(int, oldv),
                                      __builtin_bit_cast(int, v), CTRL, 0xf, 0xf, false);
  return __builtin_bit_cast(float, m);
}
// broadcast lane l (uniform literal) -> SGPR
__device__ __forceinline__ float bcast_lane(float v, int l) {
  return __builtin_bit_cast(float, __builtin_amdgcn_readlane(__builtin_bit_cast(int, v), l));
}

// ---------- cyclic tridiagonal solve M p = r, split at the barrier ----------
// M = 25I - 10(P+P^T) = 5(2I-S+)(2I-S-); local scans + seed publish pre-barrier,
// carry reconstruction + finalize post-barrier. Truncation ~2^-24 (vs 3.6e-2 tol).
__device__ __forceinline__ void solveM_pre(const float r[EPT], float pl0[EPT],
                                           float2* __restrict__ s_sc, int t) {
  float yl[EPT];
  yl[EPT - 1] = r[EPT - 1] * 0.1f;
#pragma unroll
  for (int j = EPT - 2; j >= 0; --j) yl[j] = fmaf(0.5f, yl[j + 1], r[j] * 0.1f);
  pl0[0] = 0.5f * yl[0];
#pragma unroll
  for (int j = 1; j < EPT; ++j) pl0[j] = 0.5f * (yl[j] + pl0[j - 1]);
  s_sc[t] = make_float2(yl[0], pl0[EPT - 1]);
}

__device__ __forceinline__ void solveM_post(const float pl0[EPT], float p[EPT],
                                            const float2* __restrict__ s_sc, int t) {
  const float K1[EPT] = {0.001953125f, 0.0048828125f, 0.01025390625f, 0.020751953125f,
                         0.0416259765625f, 0.08331298828125f, 0.166656494140625f,
                         K1LAST};
  float2 g[7];
#pragma unroll
  for (int k = 0; k < 7; ++k) g[k] = s_sc[(t + k - 3) & (NT - 1)];
  float c  = fmaf(LAM2, g[6].x, fmaf(LAM, g[5].x, g[4].x));
  float s1 = fmaf(LAM2, g[0].y, fmaf(LAM, g[1].y, g[2].y));
  float s2 = g[3].x;
  s2 = fmaf(LAM, g[2].x + g[4].x, s2);
  s2 = fmaf(LAM2, g[1].x + g[5].x, s2);
  float c2 = fmaf(K1LAST, s2, s1);
  float f2w = 0.5f;
#pragma unroll
  for (int j = 0; j < EPT; ++j) {
    p[j] = fmaf(c2, f2w, fmaf(c, K1[j], pl0[j]));
    f2w *= 0.5f;
  }
}

__global__ void __launch_bounds__(NT, 2)
admm_kernel(const float* __restrict__ tg, const float* __restrict__ Ag,
            const float* __restrict__ x0, float* __restrict__ out) {
  __shared__ float2 s_sc[2][NT];
  __shared__ __align__(16) float s_wq[8][12];   // per-wave 9-partials
  __shared__ float s_S[MM * MM];
  __shared__ float s_L[MM * MM];
  __shared__ float s_edge[8][2];                // [wave][0]=x[first], [1]=x[last]

  const int t = threadIdx.x;
  const int base = t * EPT;
  const int lane = t & 63, wave = t >> 6;

  // ---- load A slice (register-resident; all accesses compile-time-indexed) ----
  float A[MM][EPT];
#pragma unroll
  for (int m = 0; m < MM; ++m) {
    float4 a0 = *(const float4*)(Ag + m * NN + base);
    float4 a1 = *(const float4*)(Ag + m * NN + base + 4);
    A[m][0] = a0.x; A[m][1] = a0.y; A[m][2] = a0.z; A[m][3] = a0.w;
    A[m][4] = a1.x; A[m][5] = a1.y; A[m][6] = a1.z; A[m][7] = a1.w;
  }

  // ---- load x0, target ----
  float x[EPT], tgt[EPT];
  {
    float4 v0 = *(const float4*)(x0 + base);
    float4 v1 = *(const float4*)(x0 + base + 4);
    x[0] = v0.x; x[1] = v0.y; x[2] = v0.z; x[3] = v0.w;
    x[4] = v1.x; x[5] = v1.y; x[6] = v1.z; x[7] = v1.w;
    float4 t0 = *(const float4*)(tg + base);
    float4 t1 = *(const float4*)(tg + base + 4);
    tgt[0] = t0.x; tgt[1] = t0.y; tgt[2] = t0.z; tgt[3] = t0.w;
    tgt[4] = t1.x; tgt[5] = t1.y; tgt[6] = t1.z; tgt[7] = t1.w;
  }
  if (lane == 0)  s_edge[wave][0] = x[0];
  if (lane == 63) s_edge[wave][1] = x[7];

  // ---- b = A @ target: DPP reduce + lane-combine + readlane -> SGPRs ----
  float pq[MM];
#pragma unroll
  for (int m = 0; m < MM; ++m) {
    float s = 0.f;
#pragma unroll
    for (int j = 0; j < EPT; ++j) s = fmaf(A[m][j], tgt[j], s);
    pq[m] = wave_sum(s);
  }
  if (lane == 63) {
    *(float4*)&s_wq[wave][0] = make_float4(pq[0], pq[1], pq[2], pq[3]);
    *(float4*)&s_wq[wave][4] = make_float4(pq[4], pq[5], pq[6], pq[7]);
    s_wq[wave][8] = pq[8];
  }
  __syncthreads();
  float bb[MM];
  {
    float zv = 0.f;
    if (lane < MM) {
#pragma unroll
      for (int wv = 0; wv < 8; ++wv) zv += s_wq[wv][lane];
    }
#pragma unroll
    for (int m = 0; m < MM; ++m) bb[m] = bcast_lane(zv, m);
  }
  float bA[EPT];
#pragma unroll
  for (int j = 0; j < EPT; ++j) {
    float s = 0.f;
#pragma unroll
    for (int m = 0; m < MM; ++m) s = fmaf(bb[m], A[m][j], s);
    bA[j] = s;
  }

  // ---- S = I9 + A M^-1 A^T, keeping G columns for the GH fold ----
  float G[MM][EPT];
#pragma unroll
  for (int mc = 0; mc < MM; ++mc) {
    float rin[EPT];
#pragma unroll
    for (int j = 0; j < EPT; ++j) rin[j] = A[mc][j];
    float pl0[EPT];
    solveM_pre(rin, pl0, (float2*)&s_sc[mc & 1][0], t);
    __syncthreads();
    float gcol[EPT];
    solveM_post(pl0, gcol, (const float2*)&s_sc[mc & 1][0], t);
#pragma unroll
    for (int j = 0; j < EPT; ++j) G[mc][j] = gcol[j];
#pragma unroll
    for (int k = 0; k < MM; ++k) {
      float s = 0.f;
#pragma unroll
      for (int j = 0; j < EPT; ++j) s = fmaf(A[k][j], gcol[j], s);
      pq[k] = wave_sum(s);
    }
    if (lane == 63) {
      *(float4*)&s_wq[wave][0] = make_float4(pq[0], pq[1], pq[2], pq[3]);
      *(float4*)&s_wq[wave][4] = make_float4(pq[4], pq[5], pq[6], pq[7]);
      s_wq[wave][8] = pq[8];
    }
    __syncthreads();
    if (wave == 0 && lane < MM) {
      float s = 0.f;
#pragma unroll
      for (int wv = 0; wv < 8; ++wv) s += s_wq[wv][lane];
      s_S[lane * MM + mc] = s + ((lane == mc) ? 1.f : 0.f);
    }
  }

  // ---- Sinv (Gauss-Jordan) + Cholesky Sinv = L L^T, fused on wave 0 ----
  if (t < 64) {
    float row[2 * MM];
#pragma unroll
    for (int j = 0; j < MM; ++j) row[j] = (t < MM) ? s_S[t * MM + j] : 0.f;
#pragma unroll
    for (int j = 0; j < MM; ++j) row[MM + j] = (j == t) ? 1.f : 0.f;
#pragma unroll
    for (int pp = 0; pp < MM; ++pp) {
      float pr[2 * MM];
#pragma unroll
      for (int j = 0; j < 2 * MM; ++j) pr[j] = __shfl(row[j], pp, 64);
      float rpiv = 1.f / pr[pp];
      float fct = row[pp] * rpiv;
#pragma unroll
      for (int j = 0; j < 2 * MM; ++j)
        row[j] = (t == pp) ? pr[j] * rpiv : fmaf(-fct, pr[j], row[j]);
    }
    float crow[MM];
#pragma unroll
    for (int j = 0; j < MM; ++j) crow[j] = row[MM + j];
#pragma unroll
    for (int k = 0; k < MM; ++k) {
      float dk = __shfl(crow[k], k, 64);
      float inv = 1.f / sqrtf(dk);
      crow[k] *= inv;
#pragma unroll
      for (int jj = k + 1; jj < MM; ++jj) {
        float ljk = __shfl(crow[k], jj, 64);   // L[jj][k]
        crow[jj] = fmaf(-crow[k], ljk, crow[jj]);
      }
    }
    if (t < MM) {
#pragma unroll
      for (int j = 0; j < MM; ++j) s_L[t * MM + j] = (t >= j) ? crow[j] : 0.f;
    }
  }
  __syncthreads();

  // ---- GH[m] = sum_{k>=m} G[k] * L[k][m] (fully unrolled, register-resident) ----
  float GH[MM][EPT];
#pragma unroll
  for (int m = 0; m < MM; ++m) {
    float lcol[MM];
#pragma unroll
    for (int k = 0; k < MM; ++k) lcol[k] = s_L[k * MM + m];
#pragma unroll
    for (int j = 0; j < EPT; ++j) {
      float s = 0.f;
#pragma unroll
      for (int k = 0; k < MM; ++k)
        if (k >= m) s = fmaf(G[k][j], lcol[k], s);
      GH[m][j] = s;
    }
  }

  // ---- ADMM iterations: 2 barriers each; scaled duals (eta/10, tau/5);
  //      w eliminated: 5(w - tau5) = 5*max(x,-tau5); tau5' = x' - max(x,-tau5);
  //      soft-thresh via med3: u = v - med3(v,-lam,lam) (exact same float result) ----
  float eta10[EPT], tau5[EPT];
#pragma unroll
  for (int j = 0; j < EPT; ++j) { eta10[j] = 0.f; tau5[j] = 0.f; }
  float u7prev = 0.f;

#pragma unroll 1
  for (int it = 0; it < NIT; ++it) {
    // --- neighbors via DPP wave-shift, edge lanes via LDS ---
    float oldm = 0.f, oldn = 0.f;
    if (lane == 0)  oldm = s_edge[(wave + 7) & 7][1];
    if (lane == 63) oldn = s_edge[(wave + 1) & 7][0];
    float xm1 = dpp_shift<0x138>(oldm, x[7]);   // wave_shr1: lane i <- lane i-1
    if (it) {
      float xn8 = dpp_shift<0x130>(oldn, x[0]); // wave_shl1: lane i <- lane i+1
      eta10[7] += (xn8 - x[7]) - u7prev;        // deferred boundary dual
    }
    // --- u, m1, r ---
    float u[EPT], m1a[EPT], r[EPT];
#pragma unroll
    for (int j = 0; j < EPT; ++j) {
      float xprev = (j == 0) ? xm1 : x[j - 1];
      float v = xprev - x[j] + eta10[j];
      u[j] = v - __builtin_amdgcn_fmed3f(v, -1e-5f, 1e-5f);
      m1a[j] = fmaxf(x[j], -tau5[j]);
      r[j] = fmaf(10.f, u[j] - eta10[j], fmaf(5.f, m1a[j], bA[j]));
    }
    // --- zeta partials (from r directly) + DPP wave reduce ---
    float zp[MM];
#pragma unroll
    for (int m = 0; m < MM; ++m) {
      float s = 0.f;
#pragma unroll
      for (int j = 0; j < EPT; ++j) s = fmaf(GH[m][j], r[j], s);
      zp[m] = wave_sum(s);
    }
    if (lane == 63) {
      *(float4*)&s_wq[wave][0] = make_float4(zp[0], zp[1], zp[2], zp[3]);
      *(float4*)&s_wq[wave][4] = make_float4(zp[4], zp[5], zp[6], zp[7]);
      s_wq[wave][8] = zp[8];
    }
    // --- solveM local scans + seed publish ---
    float pl0[EPT];
    solveM_pre(r, pl0, (float2*)&s_sc[0][0], t);
    __syncthreads();                            // BARRIER A
    // --- finish solve ---
    float p[EPT];
    solveM_post(pl0, p, (const float2*)&s_sc[0][0], t);
    // --- z: lanes 0..8 combine one component each, broadcast to SGPRs ---
    float zv = 0.f;
    if (lane < MM) {
#pragma unroll
      for (int wv = 0; wv < 8; ++wv) zv += s_wq[wv][lane];
    }
    float z[MM];
#pragma unroll
    for (int m = 0; m < MM; ++m) z[m] = bcast_lane(zv, m);
    // --- x = p - GH z (in place) ---
#pragma unroll
    for (int j = 0; j < EPT; ++j) {
      float s = p[j];
#pragma unroll
      for (int m = 0; m < MM; ++m) s = fmaf(-GH[m][j], z[m], s);
      x[j] = s;
    }
    if (lane == 0)  s_edge[wave][0] = x[0];
    if (lane == 63) s_edge[wave][1] = x[7];
    // --- duals: eta j=0..6 now (j=7 deferred); tau5 = x - m1 ---
#pragma unroll
    for (int j = 0; j < EPT - 1; ++j)
      eta10[j] += (x[j + 1] - x[j]) - u[j];
#pragma unroll
    for (int j = 0; j < EPT; ++j)
      tau5[j] = x[j] - m1a[j];
    u7prev = u[7];
    __syncthreads();                            // BARRIER B
  }

  // ---- output ----
  float4 o0, o1;
  o0.x = x[0]; o0.y = x[1]; o0.z = x[2]; o0.w = x[3];
  o1.x = x[4]; o1.y = x[5]; o1.z = x[6]; o1.w = x[7];
  *(float4*)(out + base) = o0;
  *(float4*)(out + base + 4) = o1;
}

extern "C" void kernel_launch(void* const* d_in, const int* in_sizes, int n_in,
                              void* d_out, int out_size, void* d_ws, size_t ws_size,
                              hipStream_t stream) {
  const float* target = (const float*)d_in[0];
  const float* A      = (const float*)d_in[1];
  const float* x0     = (const float*)d_in[2];
  admm_kernel<<<1, NT, 0, stream>>>(target, A, x0, (float*)d_out);
}

// Round 13
// 102.745 us; speedup vs baseline: 1.4095x; 1.0032x over previous
//
#include <hip/hip_runtime.h>
#include <math.h>

#define NT 512      // 8 waves, single block, single CU
#define EPT 8       // NT*EPT = 4096
#define NN 4096
#define MM 9
#define NIT 50

#define LAM  3.90625e-3f        // 2^-8 (per-thread carry decay)
#define LAM2 1.52587890625e-5f  // 2^-16
#define K1LAST 0.3333282470703125f

// ---------- DPP cross-lane helpers (VALU pipe, no LDS) ----------
template<int CTRL, int RMASK>
__device__ __forceinline__ float dpp_add(float v) {
  int m = __builtin_amdgcn_update_dpp(0, __builtin_bit_cast(int, v), CTRL, RMASK, 0xf, false);
  return v + __builtin_bit_cast(float, m);
}
// full-wave sum; total lands in lane 63
__device__ __forceinline__ float wave_sum(float v) {
  v = dpp_add<0x111, 0xf>(v);   // row_shr:1
  v = dpp_add<0x112, 0xf>(v);   // row_shr:2
  v = dpp_add<0x114, 0xf>(v);   // row_shr:4
  v = dpp_add<0x118, 0xf>(v);   // row_shr:8
  v = dpp_add<0x142, 0xa>(v);   // row_bcast:15 -> rows 1,3
  v = dpp_add<0x143, 0xc>(v);   // row_bcast:31 -> rows 2,3
  return v;
}
// wave shift; invalid boundary lane receives `oldv`
template<int CTRL>
__device__ __forceinline__ float dpp_shift(float oldv, float v) {
  int m = __builtin_amdgcn_update_dpp(__builtin_bit_cast(int, oldv),
                                      __builtin_bit_cast(int, v), CTRL, 0xf, 0xf, false);
  return __builtin_bit_cast(float, m);
}
// broadcast lane l (uniform literal) -> SGPR
__device__ __forceinline__ float bcast_lane(float v, int l) {
  return __builtin_bit_cast(float, __builtin_amdgcn_readlane(__builtin_bit_cast(int, v), l));
}

// ---------- cyclic tridiagonal solve M p = r, split at the barrier ----------
// M = 25I - 10(P+P^T) = 5(2I-S+)(2I-S-); local scans + seed publish pre-barrier,
// carry reconstruction + finalize post-barrier. Truncation ~2^-24 (vs 3.6e-2 tol).
__device__ __forceinline__ void solveM_pre(const float r[EPT], float pl0[EPT],
                                           float2* __restrict__ s_sc, int t) {
  float yl[EPT];
  yl[EPT - 1] = r[EPT - 1] * 0.1f;
#pragma unroll
  for (int j = EPT - 2; j >= 0; --j) yl[j] = fmaf(0.5f, yl[j + 1], r[j] * 0.1f);
  pl0[0] = 0.5f * yl[0];
#pragma unroll
  for (int j = 1; j < EPT; ++j) pl0[j] = 0.5f * (yl[j] + pl0[j - 1]);
  s_sc[t] = make_float2(yl[0], pl0[EPT - 1]);
}

__device__ __forceinline__ void solveM_post(const float pl0[EPT], float p[EPT],
                                            const float2* __restrict__ s_sc, int t) {
  const float K1[EPT] = {0.001953125f, 0.0048828125f, 0.01025390625f, 0.020751953125f,
                         0.0416259765625f, 0.08331298828125f, 0.166656494140625f,
                         K1LAST};
  float2 g[7];
#pragma unroll
  for (int k = 0; k < 7; ++k) g[k] = s_sc[(t + k - 3) & (NT - 1)];
  float c  = fmaf(LAM2, g[6].x, fmaf(LAM, g[5].x, g[4].x));
  float s1 = fmaf(LAM2, g[0].y, fmaf(LAM, g[1].y, g[2].y));
  float s2 = g[3].x;
  s2 = fmaf(LAM, g[2].x + g[4].x, s2);
  s2 = fmaf(LAM2, g[1].x + g[5].x, s2);
  float c2 = fmaf(K1LAST, s2, s1);
  float f2w = 0.5f;
#pragma unroll
  for (int j = 0; j < EPT; ++j) {
    p[j] = fmaf(c2, f2w, fmaf(c, K1[j], pl0[j]));
    f2w *= 0.5f;
  }
}

__global__ void __launch_bounds__(NT, 2)
admm_kernel(const float* __restrict__ tg, const float* __restrict__ Ag,
            const float* __restrict__ x0, float* __restrict__ out) {
  __shared__ float2 s_sc[3][NT];                // 3 seed buffers (setup batches of 3; loop uses [0])
  __shared__ __align__(16) float s_wq[3][8][12];// per-wave 9-partials, 3 columns (loop uses [0])
  __shared__ float s_S[MM * MM];
  __shared__ float s_L[MM * MM];
  __shared__ float s_edge[8][2];                // [wave][0]=x[first], [1]=x[last]

  const int t = threadIdx.x;
  const int base = t * EPT;
  const int lane = t & 63, wave = t >> 6;

  // ---- load A slice (register-resident; all accesses compile-time-indexed) ----
  float A[MM][EPT];
#pragma unroll
  for (int m = 0; m < MM; ++m) {
    float4 a0 = *(const float4*)(Ag + m * NN + base);
    float4 a1 = *(const float4*)(Ag + m * NN + base + 4);
    A[m][0] = a0.x; A[m][1] = a0.y; A[m][2] = a0.z; A[m][3] = a0.w;
    A[m][4] = a1.x; A[m][5] = a1.y; A[m][6] = a1.z; A[m][7] = a1.w;
  }

  // ---- load x0, target ----
  float x[EPT], tgt[EPT];
  {
    float4 v0 = *(const float4*)(x0 + base);
    float4 v1 = *(const float4*)(x0 + base + 4);
    x[0] = v0.x; x[1] = v0.y; x[2] = v0.z; x[3] = v0.w;
    x[4] = v1.x; x[5] = v1.y; x[6] = v1.z; x[7] = v1.w;
    float4 t0 = *(const float4*)(tg + base);
    float4 t1 = *(const float4*)(tg + base + 4);
    tgt[0] = t0.x; tgt[1] = t0.y; tgt[2] = t0.z; tgt[3] = t0.w;
    tgt[4] = t1.x; tgt[5] = t1.y; tgt[6] = t1.z; tgt[7] = t1.w;
  }
  if (lane == 0)  s_edge[wave][0] = x[0];
  if (lane == 63) s_edge[wave][1] = x[7];

  // ---- b = A @ target: DPP reduce + lane-combine + readlane -> SGPRs ----
  float pq[MM];
#pragma unroll
  for (int m = 0; m < MM; ++m) {
    float s = 0.f;
#pragma unroll
    for (int j = 0; j < EPT; ++j) s = fmaf(A[m][j], tgt[j], s);
    pq[m] = wave_sum(s);
  }
  if (lane == 63) {
    *(float4*)&s_wq[0][wave][0] = make_float4(pq[0], pq[1], pq[2], pq[3]);
    *(float4*)&s_wq[0][wave][4] = make_float4(pq[4], pq[5], pq[6], pq[7]);
    s_wq[0][wave][8] = pq[8];
  }
  __syncthreads();
  float bb[MM];
  {
    float zv = 0.f;
    if (lane < MM) {
#pragma unroll
      for (int wv = 0; wv < 8; ++wv) zv += s_wq[0][wv][lane];
    }
#pragma unroll
    for (int m = 0; m < MM; ++m) bb[m] = bcast_lane(zv, m);
  }
  float bA[EPT];
#pragma unroll
  for (int j = 0; j < EPT; ++j) {
    float s = 0.f;
#pragma unroll
    for (int m = 0; m < MM; ++m) s = fmaf(bb[m], A[m][j], s);
    bA[j] = s;
  }

  // ---- S = I9 + A M^-1 A^T, batched 3 columns per barrier pair (18 -> 6 barriers,
  //      3-way ILP in the scan/reduce chains). G columns kept for the GH fold. ----
  float G[MM][EPT];
#pragma unroll
  for (int grp = 0; grp < 3; ++grp) {
    float pl3[3][EPT];
#pragma unroll
    for (int c = 0; c < 3; ++c) {
      const int mc = 3 * grp + c;
      float rin[EPT];
#pragma unroll
      for (int j = 0; j < EPT; ++j) rin[j] = A[mc][j];
      solveM_pre(rin, pl3[c], (float2*)&s_sc[c][0], t);
    }
    __syncthreads();
#pragma unroll
    for (int c = 0; c < 3; ++c) {
      const int mc = 3 * grp + c;
      float gcol[EPT];
      solveM_post(pl3[c], gcol, (const float2*)&s_sc[c][0], t);
#pragma unroll
      for (int j = 0; j < EPT; ++j) G[mc][j] = gcol[j];
#pragma unroll
      for (int k = 0; k < MM; ++k) {
        float s = 0.f;
#pragma unroll
        for (int j = 0; j < EPT; ++j) s = fmaf(A[k][j], gcol[j], s);
        pq[k] = wave_sum(s);
      }
      if (lane == 63) {
        *(float4*)&s_wq[c][wave][0] = make_float4(pq[0], pq[1], pq[2], pq[3]);
        *(float4*)&s_wq[c][wave][4] = make_float4(pq[4], pq[5], pq[6], pq[7]);
        s_wq[c][wave][8] = pq[8];
      }
    }
    __syncthreads();
    if (wave == 0 && lane < MM) {
#pragma unroll
      for (int c = 0; c < 3; ++c) {
        const int mc = 3 * grp + c;
        float s = 0.f;
#pragma unroll
        for (int wv = 0; wv < 8; ++wv) s += s_wq[c][wv][lane];
        s_S[lane * MM + mc] = s + ((lane == mc) ? 1.f : 0.f);
      }
    }
  }

  // ---- Sinv (Gauss-Jordan) + Cholesky Sinv = L L^T, fused on wave 0 ----
  // (wave0 lane i wrote row i of s_S and reads row i: same-thread, no extra barrier)
  if (t < 64) {
    float row[2 * MM];
#pragma unroll
    for (int j = 0; j < MM; ++j) row[j] = (t < MM) ? s_S[t * MM + j] : 0.f;
#pragma unroll
    for (int j = 0; j < MM; ++j) row[MM + j] = (j == t) ? 1.f : 0.f;
#pragma unroll
    for (int pp = 0; pp < MM; ++pp) {
      float pr[2 * MM];
#pragma unroll
      for (int j = 0; j < 2 * MM; ++j) pr[j] = __shfl(row[j], pp, 64);
      float rpiv = 1.f / pr[pp];
      float fct = row[pp] * rpiv;
#pragma unroll
      for (int j = 0; j < 2 * MM; ++j)
        row[j] = (t == pp) ? pr[j] * rpiv : fmaf(-fct, pr[j], row[j]);
    }
    float crow[MM];
#pragma unroll
    for (int j = 0; j < MM; ++j) crow[j] = row[MM + j];
#pragma unroll
    for (int k = 0; k < MM; ++k) {
      float dk = __shfl(crow[k], k, 64);
      float inv = 1.f / sqrtf(dk);
      crow[k] *= inv;
#pragma unroll
      for (int jj = k + 1; jj < MM; ++jj) {
        float ljk = __shfl(crow[k], jj, 64);   // L[jj][k]
        crow[jj] = fmaf(-crow[k], ljk, crow[jj]);
      }
    }
    if (t < MM) {
#pragma unroll
      for (int j = 0; j < MM; ++j) s_L[t * MM + j] = (t >= j) ? crow[j] : 0.f;
    }
  }
  __syncthreads();

  // ---- GH[m] = sum_{k>=m} G[k] * L[k][m] (fully unrolled, register-resident) ----
  float GH[MM][EPT];
#pragma unroll
  for (int m = 0; m < MM; ++m) {
    float lcol[MM];
#pragma unroll
    for (int k = 0; k < MM; ++k) lcol[k] = s_L[k * MM + m];
#pragma unroll
    for (int j = 0; j < EPT; ++j) {
      float s = 0.f;
#pragma unroll
      for (int k = 0; k < MM; ++k)
        if (k >= m) s = fmaf(G[k][j], lcol[k], s);
      GH[m][j] = s;
    }
  }

  // ---- ADMM iterations: 2 barriers each; scaled duals (eta/10, tau/5);
  //      w eliminated: 5(w - tau5) = 5*max(x,-tau5); tau5' = x' - max(x,-tau5);
  //      soft-thresh via med3: u = v - med3(v,-lam,lam) (exact same float result) ----
  float eta10[EPT], tau5[EPT];
#pragma unroll
  for (int j = 0; j < EPT; ++j) { eta10[j] = 0.f; tau5[j] = 0.f; }
  float u7prev = 0.f;

#pragma unroll 1
  for (int it = 0; it < NIT; ++it) {
    // --- neighbors via DPP wave-shift, edge lanes via LDS ---
    float oldm = 0.f, oldn = 0.f;
    if (lane == 0)  oldm = s_edge[(wave + 7) & 7][1];
    if (lane == 63) oldn = s_edge[(wave + 1) & 7][0];
    float xm1 = dpp_shift<0x138>(oldm, x[7]);   // wave_shr1: lane i <- lane i-1
    if (it) {
      float xn8 = dpp_shift<0x130>(oldn, x[0]); // wave_shl1: lane i <- lane i+1
      eta10[7] += (xn8 - x[7]) - u7prev;        // deferred boundary dual
    }
    // --- u, m1, r ---
    float u[EPT], m1a[EPT], r[EPT];
#pragma unroll
    for (int j = 0; j < EPT; ++j) {
      float xprev = (j == 0) ? xm1 : x[j - 1];
      float v = xprev - x[j] + eta10[j];
      u[j] = v - __builtin_amdgcn_fmed3f(v, -1e-5f, 1e-5f);
      m1a[j] = fmaxf(x[j], -tau5[j]);
      r[j] = fmaf(10.f, u[j] - eta10[j], fmaf(5.f, m1a[j], bA[j]));
    }
    // --- zeta partials (from r directly) + DPP wave reduce ---
    float zp[MM];
#pragma unroll
    for (int m = 0; m < MM; ++m) {
      float s = 0.f;
#pragma unroll
      for (int j = 0; j < EPT; ++j) s = fmaf(GH[m][j], r[j], s);
      zp[m] = wave_sum(s);
    }
    if (lane == 63) {
      *(float4*)&s_wq[0][wave][0] = make_float4(zp[0], zp[1], zp[2], zp[3]);
      *(float4*)&s_wq[0][wave][4] = make_float4(zp[4], zp[5], zp[6], zp[7]);
      s_wq[0][wave][8] = zp[8];
    }
    // --- solveM local scans + seed publish ---
    float pl0[EPT];
    solveM_pre(r, pl0, (float2*)&s_sc[0][0], t);
    __syncthreads();                            // BARRIER A
    // --- finish solve ---
    float p[EPT];
    solveM_post(pl0, p, (const float2*)&s_sc[0][0], t);
    // --- z: lanes 0..8 combine one component each, broadcast to SGPRs ---
    float zv = 0.f;
    if (lane < MM) {
#pragma unroll
      for (int wv = 0; wv < 8; ++wv) zv += s_wq[0][wv][lane];
    }
    float z[MM];
#pragma unroll
    for (int m = 0; m < MM; ++m) z[m] = bcast_lane(zv, m);
    // --- x = p - GH z (in place) ---
#pragma unroll
    for (int j = 0; j < EPT; ++j) {
      float s = p[j];
#pragma unroll
      for (int m = 0; m < MM; ++m) s = fmaf(-GH[m][j], z[m], s);
      x[j] = s;
    }
    if (lane == 0)  s_edge[wave][0] = x[0];
    if (lane == 63) s_edge[wave][1] = x[7];
    // --- duals: eta j=0..6 now (j=7 deferred); tau5 = x - m1 ---
#pragma unroll
    for (int j = 0; j < EPT - 1; ++j)
      eta10[j] += (x[j + 1] - x[j]) - u[j];
#pragma unroll
    for (int j = 0; j < EPT; ++j)
      tau5[j] = x[j] - m1a[j];
    u7prev = u[7];
    __syncthreads();                            // BARRIER B
  }

  // ---- output ----
  float4 o0, o1;
  o0.x = x[0]; o0.y = x[1]; o0.z = x[2]; o0.w = x[3];
  o1.x = x[4]; o1.y = x[5]; o1.z = x[6]; o1.w = x[7];
  *(float4*)(out + base) = o0;
  *(float4*)(out + base + 4) = o1;
}

extern "C" void kernel_launch(void* const* d_in, const int* in_sizes, int n_in,
                              void* d_out, int out_size, void* d_ws, size_t ws_size,
                              hipStream_t stream) {
  const float* target = (const float*)d_in[0];
  const float* A      = (const float*)d_in[1];
  const float* x0     = (const float*)d_in[2];
  admm_kernel<<<1, NT, 0, stream>>>(target, A, x0, (float*)d_out);
}